// Round 4
// baseline (364.940 us; speedup 1.0000x reference)
//
#include <hip/hip_runtime.h>
#include <hip/hip_cooperative_groups.h>
#include <stdint.h>

namespace cg = cooperative_groups;

#define NN 50000
#define NE 800000
#define CC 96
#define NL 3
#define NMT 3125          // M-tiles (16 nodes each)

// Bucketized edge lists: CAP slots per destination node. Degrees ~ Poisson(16);
// P(max degree >= 64) ~ 1e-13 -> CAP=64 safe; pos<CAP guard = non-corrupting.
#define CAP 64
#define CAPSH 6

// fp16 fragment-packed weights: per layer 6 tcol x 6 sets x 3 ks x 64 lanes x 8 fp16
#define ELEMS_PER_LAYER 55296

#define NODES_PER_GROUP (NN/8)              // 6250 (XCD fill partition)
#define GRID_BLOCKS 256                     // 1 block/CU — cooperative co-residency
#define BLOCK_THREADS 1024
#define PREP_ITEMS (NN*CC/8 + NL*288*CC + 288*CC)

typedef _Float16 f16x8 __attribute__((ext_vector_type(8)));
typedef float f32x4 __attribute__((ext_vector_type(4)));
typedef uint16_t u16x8 __attribute__((ext_vector_type(8)));

__device__ __forceinline__ uint16_t f2h(float f){
  _Float16 h = (_Float16)f;
  return __builtin_bit_cast(uint16_t, h);
}
__device__ __forceinline__ float h2f(uint16_t u){
  return (float)__builtin_bit_cast(_Float16, u);
}

// fe(tcol,g2,ks,lane,j); g2: 0-2 Wc r/z/n, 3-5 Whh r/z/n.
// B-frag (16x16x32): element (k = ks*32 + (lane>>4)*8 + j, n = lane&15).
__device__ __forceinline__ size_t frag_elem(int tcol, int g2, int ks, int lane, int j){
  return (((size_t)(tcol*6 + g2)*3 + ks)*64 + lane)*8 + j;
}

#define MFMA16(A,B,C) __builtin_amdgcn_mfma_f32_16x16x32_f16(A,B,C,0,0,0)

// One cooperative kernel = whole pipeline.
// Phase 0a: XCD-partitioned bucket fill (group = blockIdx&7 -> XCD under
//           round-robin dispatch; keeps each group's ssrc slice in one L2).
// Phase 0b: prep grid-stride (fp16 x-table cvt + weight fold/pack).
// grid.sync(), then NL layer phases (grid.sync() between them) — replaces 4
// launch/drain boundaries with 3 grid barriers.
// Layer phase: aggregate IN REGISTERS (thread gathers chunks {quad,4+quad,
// 8+quad} of its own node = exactly its lane's MFMA A-fragment; aggl LDS
// round-trip deleted, LDS = 108 KB weights only), single __syncthreads for
// weight staging, dual-GEMM + GRU epilogue, ping-pong h tables.
__global__ __launch_bounds__(1024) void k_fused(
    const int* __restrict__ srcv, const int* __restrict__ dstv,
    int* __restrict__ cursor, uint16_t* __restrict__ ssrc,
    const float4* __restrict__ x4,
    const float* __restrict__ weight, const float* __restrict__ w_ih,
    const float* __restrict__ w_hh, uint16_t* __restrict__ gw,
    uint16_t* __restrict__ xhA, uint16_t* __restrict__ xhB,
    const float* __restrict__ b_ih, const float* __restrict__ b_hh,
    float* __restrict__ out)
{
  cg::grid_group grid = cg::this_grid();
  __shared__ __align__(16) uint16_t lw[ELEMS_PER_LAYER];   // 110592 B

  const int tid  = threadIdx.x;
  const int bid  = blockIdx.x;
  const int wave = tid >> 6;
  const int lane = tid & 63;
  const int nidx = lane & 15;
  const int quad = lane >> 4;

  // ---------------- Phase 0a: bucket fill (atomic cursor = degree) ----------
  {
    int g  = bid & 7;                 // group == XCD id (round-robin heuristic)
    int bg = bid >> 3;                // 0..31 within group
    int dlo = g * NODES_PER_GROUP;
    #pragma unroll 4
    for(int e = bg*BLOCK_THREADS + tid; e < NE; e += 32*BLOCK_THREADS){
      int d = dstv[e];
      if((unsigned)(d - dlo) < (unsigned)NODES_PER_GROUP){
        int s = srcv[e];
        int pos = atomicAdd(&cursor[d], 1);
        if(pos < CAP) ssrc[((size_t)d << CAPSH) + pos] = (uint16_t)s;
      }
    }
  }
  // ---------------- Phase 0b: prep (grid-stride) ----------------------------
  {
    u16x8* xh = (u16x8*)xhA;
    const int N8   = NN*CC/8;         // 600000
    const int TOT1 = NL*288*CC;       // Wc items
    const int TOT2 = 288*CC;          // Whh items
    for(int idx = bid*BLOCK_THREADS + tid; idx < PREP_ITEMS;
        idx += GRID_BLOCKS*BLOCK_THREADS){
      if(idx < N8){
        float4 a = x4[idx*2], b = x4[idx*2+1];
        u16x8 o;
        o[0]=f2h(a.x); o[1]=f2h(a.y); o[2]=f2h(a.z); o[3]=f2h(a.w);
        o[4]=f2h(b.x); o[5]=f2h(b.y); o[6]=f2h(b.z); o[7]=f2h(b.w);
        xh[idx] = o;
      } else {
        int pidx = idx - N8;
        if(pidx < TOT1){
          int k = pidx % CC;
          int col = (pidx / CC) % 288;
          int l = pidx / (CC*288);
          // Wc[k][col] = sum_k2 weight[l][k][k2] * w_ih[col][k2]
          const float4* wr = (const float4*)(weight + (size_t)(l*CC + k)*CC);
          const float4* ir = (const float4*)(w_ih + (size_t)col*CC);
          float acc = 0.f;
          #pragma unroll 4
          for(int k2=0;k2<CC/4;k2++){
            float4 a = wr[k2], b = ir[k2];
            acc += a.x*b.x + a.y*b.y + a.z*b.z + a.w*b.w;
          }
          int g = col / 96, cg = col % 96;
          int tcol = cg >> 4, n = cg & 15;
          int ks = k >> 5, r = (k & 31) >> 3, j = k & 7;
          int ln = r*16 + n;
          gw[(size_t)l*ELEMS_PER_LAYER + frag_elem(tcol, g, ks, ln, j)] = f2h(acc);
        } else {
          int idx2 = pidx - TOT1;
          if(idx2 < TOT2){
            int k = idx2 % CC;
            int col = idx2 / CC;
            uint16_t h = f2h(w_hh[(size_t)col*CC + k]);  // gh: B[k][col] = w_hh[col][k]
            int g = col / 96, cg = col % 96;
            int tcol = cg >> 4, n = cg & 15;
            int ks = k >> 5, r = (k & 31) >> 3, j = k & 7;
            int ln = r*16 + n;
            size_t fe = frag_elem(tcol, 3+g, ks, ln, j);
            #pragma unroll
            for(int l=0;l<NL;l++) gw[(size_t)l*ELEMS_PER_LAYER + fe] = h;
          }
        }
      }
    }
  }
  grid.sync();                         // buckets + tables ready, device-visible

  // ---------------- Layer phases --------------------------------------------
  const int mtile = wave*256 + bid;    // cyclic over 16 waves x 256 blocks
  const bool valid = (mtile < NMT);
  const int mt = valid ? mtile : 0;
  uint16_t* cur = xhA;
  uint16_t* nxt = xhB;

  for(int l=0; l<NL; l++){
    const uint16_t* gw_l = gw + (size_t)l*ELEMS_PER_LAYER;

    // h-row A fragments (global, long latency) — issued first
    f16x8 ax[3];
    {
      size_t arow = (size_t)(mt*16 + nidx)*CC;
      #pragma unroll
      for(int ks=0; ks<3; ks++)
        ax[ks] = *reinterpret_cast<const f16x8*>(cur + arow + ks*32 + quad*8);
    }

    // stage weights: 6912 uint4 chunks over 1024 threads
    {
      const uint4* src = (const uint4*)gw_l;
      uint4* dst = (uint4*)lw;
      #pragma unroll
      for(int i=0;i<7;i++){
        int chunk = i*1024 + tid;
        if(chunk < ELEMS_PER_LAYER/8) dst[chunk] = src[chunk];
      }
    }

    // register aggregation: this thread's node = mt*16+nidx, chunks
    // {quad, 4+quad, 8+quad} == its own A-fragments as[0..2].
    // Per load instr the 4 quad-lanes of a node cover 64B consecutive of the
    // source row -> clean 64B segments, 16 rows per wave per instruction.
    float a0[8], a1[8], a2[8];
    #pragma unroll
    for(int t=0;t<8;t++){ a0[t]=0.f; a1[t]=0.f; a2[t]=0.f; }
    if(valid){
      int node = mt*16 + nidx;
      int cnt = cursor[node]; if(cnt > CAP) cnt = CAP;   // cannot trigger
      const u16x8* xg = (const u16x8*)cur;
      int j0 = node << CAPSH;
      int j1 = j0 + cnt;
      int j = j0;
      for(; j+4 <= j1; j+=4){
        ushort4 sv = *reinterpret_cast<const ushort4*>(ssrc + j);  // 8B aligned
        size_t b0 = (size_t)sv.x*12 + quad;
        size_t b1 = (size_t)sv.y*12 + quad;
        size_t b2 = (size_t)sv.z*12 + quad;
        size_t b3 = (size_t)sv.w*12 + quad;
        u16x8 v00=xg[b0],   v01=xg[b0+4], v02=xg[b0+8];
        u16x8 v10=xg[b1],   v11=xg[b1+4], v12=xg[b1+8];
        u16x8 v20=xg[b2],   v21=xg[b2+4], v22=xg[b2+8];
        u16x8 v30=xg[b3],   v31=xg[b3+4], v32=xg[b3+8];
        #pragma unroll
        for(int t=0;t<8;t++){
          a0[t] += (h2f(v00[t])+h2f(v10[t])) + (h2f(v20[t])+h2f(v30[t]));
          a1[t] += (h2f(v01[t])+h2f(v11[t])) + (h2f(v21[t])+h2f(v31[t]));
          a2[t] += (h2f(v02[t])+h2f(v12[t])) + (h2f(v22[t])+h2f(v32[t]));
        }
      }
      for(; j < j1; j++){
        size_t b = (size_t)ssrc[j]*12 + quad;
        u16x8 v0=xg[b], v1=xg[b+4], v2=xg[b+8];
        #pragma unroll
        for(int t=0;t<8;t++){ a0[t]+=h2f(v0[t]); a1[t]+=h2f(v1[t]); a2[t]+=h2f(v2[t]); }
      }
    }
    __syncthreads();                    // weights staged (agg is thread-private)

    if(valid){
      f16x8 as[3];
      #pragma unroll
      for(int t=0;t<8;t++){
        as[0][t]=(_Float16)a0[t]; as[1][t]=(_Float16)a1[t]; as[2][t]=(_Float16)a2[t];
      }

      #pragma unroll 1
      for(int tcol=0; tcol<6; tcol++){
        f32x4 air = {0.f,0.f,0.f,0.f}, aiz = {0.f,0.f,0.f,0.f}, ain = {0.f,0.f,0.f,0.f};
        f32x4 ahr = {0.f,0.f,0.f,0.f}, ahz = {0.f,0.f,0.f,0.f}, ahn = {0.f,0.f,0.f,0.f};

        #pragma unroll
        for(int ks=0; ks<3; ks++){
          const uint16_t* base = lw + (((size_t)tcol*6)*3 + ks)*512 + lane*8;
          #define BFRAG(g2) (*reinterpret_cast<const f16x8*>(base + (size_t)(g2)*3*512))
          air = MFMA16(as[ks], BFRAG(0), air);
          aiz = MFMA16(as[ks], BFRAG(1), aiz);
          ain = MFMA16(as[ks], BFRAG(2), ain);
          ahr = MFMA16(ax[ks], BFRAG(3), ahr);
          ahz = MFMA16(ax[ks], BFRAG(4), ahz);
          ahn = MFMA16(ax[ks], BFRAG(5), ahn);
          #undef BFRAG
        }

        int c = tcol*16 + nidx;
        float bir_ = b_ih[c], biz_ = b_ih[CC+c], bin_ = b_ih[2*CC+c];
        float bhr_ = b_hh[c], bhz_ = b_hh[CC+c], bhn_ = b_hh[2*CC+c];

        #pragma unroll
        for(int r=0;r<4;r++){
          int node = mtile*16 + quad*4 + r;   // C/D: row = quad*4 + reg
          float ir  = air[r] + bir_;
          float iz  = aiz[r] + biz_;
          float in_ = ain[r] + bin_;
          float hr  = ahr[r] + bhr_;
          float hz  = ahz[r] + bhz_;
          float hn  = ahn[r] + bhn_;
          float rg = 1.f/(1.f + __expf(-(ir+hr)));
          float zg = 1.f/(1.f + __expf(-(iz+hz)));
          float nv = in_ + rg*hn;
          float av = fminf(fabsf(nv), 15.f);
          float e2 = __expf(2.f*av);
          float tg = 1.f - 2.f/(e2 + 1.f);
          tg = (nv < 0.f)? -tg : tg;
          size_t oi = (size_t)node*CC + c;
          float hp = h2f(cur[oi]);            // previous h
          float h = (1.f - zg)*tg + zg*hp;
          if(l == NL-1) out[oi] = h;          // final layer: f32 output
          else          nxt[oi] = f2h(h);     // fp16 ping-pong
        }
      }
    }

    if(l < NL-1) grid.sync();           // h table device-visible for next layer
    uint16_t* tswap = cur; cur = nxt; nxt = tswap;
  }
}

extern "C" void kernel_launch(void* const* d_in, const int* in_sizes, int n_in,
                              void* d_out, int out_size, void* d_ws, size_t ws_size,
                              hipStream_t stream){
  const float* x0     = (const float*)d_in[0];
  const int*   ei     = (const int*)d_in[1];
  const float* weight = (const float*)d_in[2];
  const float* w_ih   = (const float*)d_in[3];
  const float* w_hh   = (const float*)d_in[4];
  const float* b_ih   = (const float*)d_in[5];
  const float* b_hh   = (const float*)d_in[6];
  float* out = (float*)d_out;

  const int* srcv = ei;        // edge_index[0]
  const int* dstv = ei + NE;   // edge_index[1]

  char* ws = (char*)d_ws;
  size_t off = 0;
  auto carve = [&](size_t bytes)->char*{
    char* p = ws + off;
    off += (bytes + 255) & ~(size_t)255;
    return p;
  };
  int* cursor     = (int*)carve((size_t)NN*4);                   // degree counters
  uint16_t* ssrc  = (uint16_t*)carve((size_t)NN*CAP*2);          // bucketized src ids
  uint16_t* xhA   = (uint16_t*)carve((size_t)NN*CC*2);           // fp16 h ping
  uint16_t* xhB   = (uint16_t*)carve((size_t)NN*CC*2);           // fp16 h pong
  uint16_t* gw    = (uint16_t*)carve((size_t)NL*ELEMS_PER_LAYER*2);

  hipMemsetAsync(cursor, 0, (size_t)NN*4, stream);

  const float4* x4 = (const float4*)x0;
  void* args[] = {
    (void*)&srcv, (void*)&dstv, (void*)&cursor, (void*)&ssrc,
    (void*)&x4, (void*)&weight, (void*)&w_ih, (void*)&w_hh, (void*)&gw,
    (void*)&xhA, (void*)&xhB, (void*)&b_ih, (void*)&b_hh, (void*)&out
  };
  hipLaunchCooperativeKernel((const void*)k_fused,
                             dim3(GRID_BLOCKS), dim3(BLOCK_THREADS),
                             args, 0, stream);
}